// Round 3
// baseline (37795.886 us; speedup 1.0000x reference)
//
#include <hip/hip_runtime.h>

// LSTM seq2seq: 1000 encoder + 1000 decoder steps, B=512, H=512, IN=OUT=1.
// Persistent PLAIN-launch kernel (cooperative launch silently fails in this
// harness -> rounds 1-2 produced zero output). 256 blocks x 256 threads,
// 1 block/CU on the 256-CU MI355X; co-residency by grid<=CU-count.
// Block (rb,hb): rb=bid>>5 owns batch rows [rb*64, rb*64+64); hb=bid&31 owns
// hidden cols [hb*16, hb*16+16) -> 64 gate columns (4 gates x 16).
// Sync: per-row-group (32 blocks) monotonic counter barrier in d_ws.
// Numerics: h in fp16; W = W_hi(fp16) + W_lo(fp16*2048)/2048, BOTH in
// registers (256 VGPRs/wave), two MFMA passes (f32 accum). Rest fp32.

typedef _Float16 f16x8 __attribute__((ext_vector_type(8)));
typedef _Float16 f16x4 __attribute__((ext_vector_type(4)));
typedef float    f32x4 __attribute__((ext_vector_type(4)));

__global__ void init_zero(float* __restrict__ out, int nout,
                          float* __restrict__ wsf, int nws) {
  int i = blockIdx.x*blockDim.x + threadIdx.x;
  int st = gridDim.x*blockDim.x;
  for (int j=i; j<nout; j+=st) out[j] = 0.f;
  for (int j=i; j<nws;  j+=st) wsf[j] = 0.f;
}

__global__ __launch_bounds__(256, 1) void lstm_main(
    const float* __restrict__ xin,                              // [1000][512]
    const float* __restrict__ encWih, const float* __restrict__ encWhh,
    const float* __restrict__ enc_bih, const float* __restrict__ enc_bhh,
    const float* __restrict__ decWih, const float* __restrict__ decWhh,
    const float* __restrict__ dec_bih, const float* __restrict__ dec_bhh,
    const float* __restrict__ linW, const float* __restrict__ linb,
    float* __restrict__ out,                                    // [1000][512]
    _Float16* __restrict__ hbuf,                                // [2][512][512]
    int* __restrict__ cnt)                                      // 8 counters, 256B apart
{
  __shared__ float gates[64][68];   // 17408 B static; +4 pad kills stride conflicts

  const int bid = blockIdx.x, tid = threadIdx.x;
  const int rb = bid >> 5, hb = bid & 31;
  const int wid = tid >> 6, lane = tid & 63;
  const int wrow = wid >> 1, wcol = wid & 1;         // wave grid 2x2
  const int lcol = lane & 15, lq = lane >> 4, kq = lq*8;

  // cell-update role: thread owns 4 cells (b_local, hidden cols u0..u0+3)
  const int b_local = tid >> 2, u0 = (tid & 3)*4;
  const int bg = rb*64 + b_local;
  const int jh0 = hb*16 + u0;

  float linw[4];
  #pragma unroll
  for (int u=0; u<4; ++u) linw[u] = linW[jh0+u];
  const float linbv = linb[0];

  f16x8 wHi[2][16], wLo[2][16];     // [coltile][kstep], 256 VGPRs
  float biasv[16], wihv[16];        // [gate*4+u]
  float c[4] = {0.f, 0.f, 0.f, 0.f};
  int* mycnt = cnt + rb*64;         // 256B apart per group

  auto loadW = [&](const float* Whh, const float* bih, const float* bhh,
                   const float* Wih) {
    #pragma unroll
    for (int ct=0; ct<2; ++ct) {
      const int g = wcol*2 + ct;                       // gate index 0..3
      const float* wr = Whh + (size_t)(g*512 + hb*16 + lcol)*512;
      #pragma unroll
      for (int ks=0; ks<16; ++ks) {
        f16x8 hi, lo;
        #pragma unroll
        for (int i=0; i<8; ++i) {
          float w = wr[ks*32 + kq + i];
          _Float16 hh = (_Float16)w;
          float hf = (float)hh;
          float rem = (w - hf)*2048.0f;
          if (fabsf(hf) < 6.104e-5f) { hh = (_Float16)0.0f; rem = w*2048.0f; }  // fp16-subnormal guard
          hi[i] = hh; lo[i] = (_Float16)rem;
        }
        wHi[ct][ks] = hi; wLo[ct][ks] = lo;
      }
    }
    #pragma unroll
    for (int g=0; g<4; ++g) {
      #pragma unroll
      for (int u=0; u<4; ++u) {
        int j = g*512 + jh0 + u;
        biasv[g*4+u] = bih[j] + bhh[j];
        wihv[g*4+u]  = Wih[j];          // IN==1: Wih is [2048][1]
      }
    }
  };

  loadW(encWhh, enc_bih, enc_bhh, encWih);

  int epoch = 0;
  for (int s=0; s<2000; ++s) {
    if (s == 1000) {                       // enc -> dec weight switch (post-barrier, safe)
      loadW(decWhh, dec_bih, dec_bhh, decWih);
    }
    const bool dec = (s >= 1000);
    const int td = s - 1000;
    const _Float16* hr = hbuf + (size_t)((s+1)&1)*(512*512);  // reads h_{s-1}
    _Float16*       hw = hbuf + (size_t)( s   &1)*(512*512);  // writes h_s

    // ---- gates = h @ W^T  (2-pass MFMA, wave tile 32 rows x 32 gate cols) ----
    f32x4 accH[2][2], accL[2][2];
    #pragma unroll
    for (int rt=0; rt<2; ++rt)
      #pragma unroll
      for (int ctt=0; ctt<2; ++ctt) {
        accH[rt][ctt] = {0.f,0.f,0.f,0.f};
        accL[rt][ctt] = {0.f,0.f,0.f,0.f};
      }

    const _Float16* hr0 = hr + (size_t)(rb*64 + wrow*32 + lcol)*512 + kq;
    const _Float16* hr1 = hr0 + 16*512;

    #pragma unroll
    for (int ks=0; ks<16; ++ks) {
      const f16x8 a0  = *reinterpret_cast<const f16x8*>(hr0 + ks*32);
      const f16x8 a1  = *reinterpret_cast<const f16x8*>(hr1 + ks*32);
      accH[0][0] = __builtin_amdgcn_mfma_f32_16x16x32_f16(a0, wHi[0][ks], accH[0][0], 0,0,0);
      accH[1][0] = __builtin_amdgcn_mfma_f32_16x16x32_f16(a1, wHi[0][ks], accH[1][0], 0,0,0);
      accH[0][1] = __builtin_amdgcn_mfma_f32_16x16x32_f16(a0, wHi[1][ks], accH[0][1], 0,0,0);
      accH[1][1] = __builtin_amdgcn_mfma_f32_16x16x32_f16(a1, wHi[1][ks], accH[1][1], 0,0,0);
      accL[0][0] = __builtin_amdgcn_mfma_f32_16x16x32_f16(a0, wLo[0][ks], accL[0][0], 0,0,0);
      accL[1][0] = __builtin_amdgcn_mfma_f32_16x16x32_f16(a1, wLo[0][ks], accL[1][0], 0,0,0);
      accL[0][1] = __builtin_amdgcn_mfma_f32_16x16x32_f16(a0, wLo[1][ks], accL[0][1], 0,0,0);
      accL[1][1] = __builtin_amdgcn_mfma_f32_16x16x32_f16(a1, wLo[1][ks], accL[1][1], 0,0,0);
    }

    // C-layout (m89): col = lane&15, row = (lane>>4)*4 + i
    #pragma unroll
    for (int rt=0; rt<2; ++rt) {
      #pragma unroll
      for (int ctt=0; ctt<2; ++ctt) {
        f32x4 v = accH[rt][ctt] + accL[rt][ctt]*(1.0f/2048.0f);
        const int col  = wcol*32 + ctt*16 + lcol;
        const int row0 = wrow*32 + rt*16 + lq*4;
        #pragma unroll
        for (int i=0; i<4; ++i) gates[row0+i][col] = v[i];
      }
    }
    __syncthreads();

    // ---- pointwise LSTM cell update (fp32) ----
    float x;
    if (!dec) x = xin[(size_t)s*512 + bg];
    else      x = (td > 0) ? out[(size_t)(td-1)*512 + bg] : 0.0f;

    const f32x4 gi = *reinterpret_cast<const f32x4*>(&gates[b_local][ 0 + u0]);
    const f32x4 gf = *reinterpret_cast<const f32x4*>(&gates[b_local][16 + u0]);
    const f32x4 gg = *reinterpret_cast<const f32x4*>(&gates[b_local][32 + u0]);
    const f32x4 go = *reinterpret_cast<const f32x4*>(&gates[b_local][48 + u0]);

    f16x4 hv4;
    float sp = 0.f;
    #pragma unroll
    for (int u=0; u<4; ++u) {
      float ai = gi[u] + biasv[ 0+u] + x*wihv[ 0+u];
      float af = gf[u] + biasv[ 4+u] + x*wihv[ 4+u];
      float ag = gg[u] + biasv[ 8+u] + x*wihv[ 8+u];
      float ao = go[u] + biasv[12+u] + x*wihv[12+u];
      float iv = 1.0f/(1.0f + expf(-ai));
      float fv = 1.0f/(1.0f + expf(-af));
      float gv = tanhf(ag);
      float ov = 1.0f/(1.0f + expf(-ao));
      float cn = fv*c[u] + iv*gv;
      c[u] = cn;
      float hv = ov*tanhf(cn);
      hv4[u] = (_Float16)hv;
      sp += hv*linw[u];
    }
    *reinterpret_cast<f16x4*>(hw + (size_t)bg*512 + jh0) = hv4;  // 8B fp16 store

    if (dec) {  // pred partial: reduce 4 lanes sharing b, one atomicAdd into d_out
      sp += __shfl_xor(sp, 1);
      sp += __shfl_xor(sp, 2);
      if ((tid & 3) == 0) {
        float v = sp + (hb == 0 ? linbv : 0.f);
        atomicAdd(&out[(size_t)td*512 + bg], v);
      }
    }

    // ---- row-group barrier (32 blocks), monotonic counter ----
    if (s != 1999) {
      __syncthreads();
      ++epoch;
      if (tid == 0) {
        __builtin_amdgcn_fence(__ATOMIC_RELEASE, "agent");
        __hip_atomic_fetch_add(mycnt, 1, __ATOMIC_RELAXED, __HIP_MEMORY_SCOPE_AGENT);
        const int target = 32*epoch;
        while (__hip_atomic_load(mycnt, __ATOMIC_RELAXED, __HIP_MEMORY_SCOPE_AGENT) < target)
          __builtin_amdgcn_s_sleep(1);
        __builtin_amdgcn_fence(__ATOMIC_ACQUIRE, "agent");
      }
      __syncthreads();
    }
  }
}

extern "C" void kernel_launch(void* const* d_in, const int* in_sizes, int n_in,
                              void* d_out, int out_size, void* d_ws, size_t ws_size,
                              hipStream_t stream) {
  const float* xin     = (const float*)d_in[0];
  const float* encWih  = (const float*)d_in[1];
  const float* encWhh  = (const float*)d_in[2];
  const float* enc_bih = (const float*)d_in[3];
  const float* enc_bhh = (const float*)d_in[4];
  const float* decWih  = (const float*)d_in[5];
  const float* decWhh  = (const float*)d_in[6];
  const float* dec_bih = (const float*)d_in[7];
  const float* dec_bhh = (const float*)d_in[8];
  const float* linW    = (const float*)d_in[9];
  const float* linb    = (const float*)d_in[10];
  float* out = (float*)d_out;
  char* ws = (char*)d_ws;
  int* cnt = (int*)ws;                          // [0,4096): barrier counters
  _Float16* hbuf = (_Float16*)(ws + 4096);      // [4096, 4096+1MB): h double buffer

  // zero d_out (pred accumulator) + counters + h buffers, every launch
  init_zero<<<512, 256, 0, stream>>>(out, 1000*512, (float*)ws,
                                     (4096 + 2*512*512*2)/4);

  // PLAIN launch (cooperative launch silently no-ops in this harness).
  // 256 blocks <= 256 CUs -> all blocks co-resident; sync is our own
  // per-row-group counter barrier in d_ws.
  lstm_main<<<dim3(256), dim3(256), 0, stream>>>(
      xin, encWih, encWhh, enc_bih, enc_bhh,
      decWih, decWhh, dec_bih, dec_bhh,
      linW, linb, out, hbuf, cnt);
}

// Round 4
// 29284.351 us; speedup vs baseline: 1.2907x; 1.2907x over previous
//
#include <hip/hip_runtime.h>

// LSTM seq2seq: 1000 encoder + 1000 decoder steps, B=512, H=512, IN=OUT=1.
// Persistent PLAIN-launch kernel; 256 blocks x 256 threads, 1 block/CU.
// Block (rb,hb): rb=bid>>5 owns batch rows [rb*64,+64); hb=bid&31 owns hidden
// cols [hb*16,+16) -> 64 gate columns. Sync: per-row-group (32 blocks)
// monotonic counter barrier in d_ws.
// ROUND 4: fence-free sync. Cross-block data (h, feedback, counters) moves via
// RELAXED agent-scope atomics (sc0 sc1 -> LLC coherence point). No
// buffer_wbl2/buffer_inv per step (round-3 killer: 4.5GB HBM fetch from
// per-step full-L2 writeback+invalidate). init_zero also uses agent atomic
// stores so no dirty L2 zero-lines can evict over LLC atomic results.
// Numerics: h fp16; W = W_hi(fp16) + W_lo(fp16*2048)/2048 in registers,
// two MFMA passes (f32 accum). Rest fp32.  [round-3 absmax 6.1e-5, 4.6x margin]

typedef _Float16 f16x8 __attribute__((ext_vector_type(8)));
typedef _Float16 f16x4 __attribute__((ext_vector_type(4)));
typedef float    f32x4 __attribute__((ext_vector_type(4)));
typedef unsigned long long u64;

__device__ __forceinline__ void store_h8_llc(_Float16* p, f16x4 v) {
  __hip_atomic_store((u64*)p, __builtin_bit_cast(u64, v),
                     __ATOMIC_RELAXED, __HIP_MEMORY_SCOPE_AGENT);
}
__device__ __forceinline__ f16x8 load_h16_llc(const _Float16* p) {
  u64 lo = __hip_atomic_load((const u64*)p,       __ATOMIC_RELAXED, __HIP_MEMORY_SCOPE_AGENT);
  u64 hi = __hip_atomic_load((const u64*)(p + 4), __ATOMIC_RELAXED, __HIP_MEMORY_SCOPE_AGENT);
  union { u64 q[2]; f16x8 v; } u; u.q[0] = lo; u.q[1] = hi; return u.v;
}

__global__ void init_zero(float* __restrict__ out, int nout,
                          float* __restrict__ wsf, int nws) {
  int i = blockIdx.x*blockDim.x + threadIdx.x;
  int st = gridDim.x*blockDim.x;
  // agent-scope write-through stores: nothing left dirty in any L2
  for (int j=i; j<nout; j+=st)
    __hip_atomic_store(&out[j], 0.f, __ATOMIC_RELAXED, __HIP_MEMORY_SCOPE_AGENT);
  for (int j=i; j<nws;  j+=st)
    __hip_atomic_store(&wsf[j], 0.f, __ATOMIC_RELAXED, __HIP_MEMORY_SCOPE_AGENT);
}

__global__ __launch_bounds__(256, 1) void lstm_main(
    const float* __restrict__ xin,                              // [1000][512]
    const float* __restrict__ encWih, const float* __restrict__ encWhh,
    const float* __restrict__ enc_bih, const float* __restrict__ enc_bhh,
    const float* __restrict__ decWih, const float* __restrict__ decWhh,
    const float* __restrict__ dec_bih, const float* __restrict__ dec_bhh,
    const float* __restrict__ linW, const float* __restrict__ linb,
    float* __restrict__ out,                                    // [1000][512]
    _Float16* __restrict__ hbuf,                                // [2][512][512]
    int* __restrict__ cnt)                                      // 8 counters, 1KB apart
{
  __shared__ float gates[64][68];   // 17408 B static; +4 pad kills stride conflicts

  const int bid = blockIdx.x, tid = threadIdx.x;
  const int rb = bid >> 5, hb = bid & 31;
  const int wid = tid >> 6, lane = tid & 63;
  const int wrow = wid >> 1, wcol = wid & 1;         // wave grid 2x2
  const int lcol = lane & 15, lq = lane >> 4, kq = lq*8;

  // cell-update role: thread owns 4 cells (b_local, hidden cols u0..u0+3)
  const int b_local = tid >> 2, u0 = (tid & 3)*4;
  const int bg = rb*64 + b_local;
  const int jh0 = hb*16 + u0;

  float linw[4];
  #pragma unroll
  for (int u=0; u<4; ++u) linw[u] = linW[jh0+u];
  const float linbv = linb[0];

  f16x8 wHi[2][16], wLo[2][16];     // [coltile][kstep], 256 VGPRs
  float biasv[16], wihv[16];        // [gate*4+u]
  float c[4] = {0.f, 0.f, 0.f, 0.f};
  int* mycnt = cnt + rb*256;        // 1KB apart per group

  auto loadW = [&](const float* Whh, const float* bih, const float* bhh,
                   const float* Wih) {
    #pragma unroll
    for (int ct=0; ct<2; ++ct) {
      const int g = wcol*2 + ct;                       // gate index 0..3
      const float* wr = Whh + (size_t)(g*512 + hb*16 + lcol)*512;
      #pragma unroll
      for (int ks=0; ks<16; ++ks) {
        f16x8 hi, lo;
        #pragma unroll
        for (int i=0; i<8; ++i) {
          float w = wr[ks*32 + kq + i];
          _Float16 hh = (_Float16)w;
          float hf = (float)hh;
          float rem = (w - hf)*2048.0f;
          if (fabsf(hf) < 6.104e-5f) { hh = (_Float16)0.0f; rem = w*2048.0f; }  // fp16-subnormal guard
          hi[i] = hh; lo[i] = (_Float16)rem;
        }
        wHi[ct][ks] = hi; wLo[ct][ks] = lo;
      }
    }
    #pragma unroll
    for (int g=0; g<4; ++g) {
      #pragma unroll
      for (int u=0; u<4; ++u) {
        int j = g*512 + jh0 + u;
        biasv[g*4+u] = bih[j] + bhh[j];
        wihv[g*4+u]  = Wih[j];          // IN==1: Wih is [2048][1]
      }
    }
  };

  loadW(encWhh, enc_bih, enc_bhh, encWih);

  int epoch = 0;
  for (int s=0; s<2000; ++s) {
    if (s == 1000) {                       // enc -> dec weight switch (post-barrier, safe)
      loadW(decWhh, dec_bih, dec_bhh, decWih);
    }
    const bool dec = (s >= 1000);
    const int td = s - 1000;
    const _Float16* hr = hbuf + (size_t)((s+1)&1)*(512*512);  // reads h_{s-1}
    _Float16*       hw = hbuf + (size_t)( s   &1)*(512*512);  // writes h_s

    // ---- gates = h @ W^T  (2-pass MFMA, wave tile 32 rows x 32 gate cols) ----
    f32x4 accH[2][2], accL[2][2];
    #pragma unroll
    for (int rt=0; rt<2; ++rt)
      #pragma unroll
      for (int ctt=0; ctt<2; ++ctt) {
        accH[rt][ctt] = {0.f,0.f,0.f,0.f};
        accL[rt][ctt] = {0.f,0.f,0.f,0.f};
      }

    const _Float16* hr0 = hr + (size_t)(rb*64 + wrow*32 + lcol)*512 + kq;
    const _Float16* hr1 = hr0 + 16*512;

    #pragma unroll
    for (int ks=0; ks<16; ++ks) {
      const f16x8 a0 = load_h16_llc(hr0 + ks*32);   // sc0 sc1: fresh from LLC
      const f16x8 a1 = load_h16_llc(hr1 + ks*32);
      accH[0][0] = __builtin_amdgcn_mfma_f32_16x16x32_f16(a0, wHi[0][ks], accH[0][0], 0,0,0);
      accH[1][0] = __builtin_amdgcn_mfma_f32_16x16x32_f16(a1, wHi[0][ks], accH[1][0], 0,0,0);
      accH[0][1] = __builtin_amdgcn_mfma_f32_16x16x32_f16(a0, wHi[1][ks], accH[0][1], 0,0,0);
      accH[1][1] = __builtin_amdgcn_mfma_f32_16x16x32_f16(a1, wHi[1][ks], accH[1][1], 0,0,0);
      accL[0][0] = __builtin_amdgcn_mfma_f32_16x16x32_f16(a0, wLo[0][ks], accL[0][0], 0,0,0);
      accL[1][0] = __builtin_amdgcn_mfma_f32_16x16x32_f16(a1, wLo[0][ks], accL[1][0], 0,0,0);
      accL[0][1] = __builtin_amdgcn_mfma_f32_16x16x32_f16(a0, wLo[1][ks], accL[0][1], 0,0,0);
      accL[1][1] = __builtin_amdgcn_mfma_f32_16x16x32_f16(a1, wLo[1][ks], accL[1][1], 0,0,0);
    }

    // C-layout (m89): col = lane&15, row = (lane>>4)*4 + i
    #pragma unroll
    for (int rt=0; rt<2; ++rt) {
      #pragma unroll
      for (int ctt=0; ctt<2; ++ctt) {
        f32x4 v = accH[rt][ctt] + accL[rt][ctt]*(1.0f/2048.0f);
        const int col  = wcol*32 + ctt*16 + lcol;
        const int row0 = wrow*32 + rt*16 + lq*4;
        #pragma unroll
        for (int i=0; i<4; ++i) gates[row0+i][col] = v[i];
      }
    }
    __syncthreads();

    // ---- pointwise LSTM cell update (fp32) ----
    float x;
    if (!dec) x = xin[(size_t)s*512 + bg];
    else      x = (td > 0) ? __hip_atomic_load(&out[(size_t)(td-1)*512 + bg],
                                               __ATOMIC_RELAXED, __HIP_MEMORY_SCOPE_AGENT)
                           : 0.0f;

    const f32x4 gi = *reinterpret_cast<const f32x4*>(&gates[b_local][ 0 + u0]);
    const f32x4 gf = *reinterpret_cast<const f32x4*>(&gates[b_local][16 + u0]);
    const f32x4 gg = *reinterpret_cast<const f32x4*>(&gates[b_local][32 + u0]);
    const f32x4 go = *reinterpret_cast<const f32x4*>(&gates[b_local][48 + u0]);

    f16x4 hv4;
    float sp = 0.f;
    #pragma unroll
    for (int u=0; u<4; ++u) {
      float ai = gi[u] + biasv[ 0+u] + x*wihv[ 0+u];
      float af = gf[u] + biasv[ 4+u] + x*wihv[ 4+u];
      float ag = gg[u] + biasv[ 8+u] + x*wihv[ 8+u];
      float ao = go[u] + biasv[12+u] + x*wihv[12+u];
      float iv = 1.0f/(1.0f + expf(-ai));
      float fv = 1.0f/(1.0f + expf(-af));
      float gv = tanhf(ag);
      float ov = 1.0f/(1.0f + expf(-ao));
      float cn = fv*c[u] + iv*gv;
      c[u] = cn;
      float hv = ov*tanhf(cn);
      hv4[u] = (_Float16)hv;
      sp += hv*linw[u];
    }
    store_h8_llc(hw + (size_t)bg*512 + jh0, hv4);   // 8B write-through to LLC

    if (dec) {  // pred partial: reduce 4 lanes sharing b, one atomicAdd into d_out
      sp += __shfl_xor(sp, 1);
      sp += __shfl_xor(sp, 2);
      if ((tid & 3) == 0) {
        float v = sp + (hb == 0 ? linbv : 0.f);
        __hip_atomic_fetch_add(&out[(size_t)td*512 + bg], v,
                               __ATOMIC_RELAXED, __HIP_MEMORY_SCOPE_AGENT);
      }
    }

    // ---- row-group barrier (32 blocks), fence-free monotonic counter ----
    if (s != 1999) {
      asm volatile("s_waitcnt vmcnt(0)" ::: "memory");  // every wave: h stores at LLC
      __syncthreads();
      ++epoch;
      if (tid == 0) {
        __hip_atomic_fetch_add(mycnt, 1, __ATOMIC_RELAXED, __HIP_MEMORY_SCOPE_AGENT);
        const int target = 32*epoch;
        while (__hip_atomic_load(mycnt, __ATOMIC_RELAXED, __HIP_MEMORY_SCOPE_AGENT) < target)
          __builtin_amdgcn_s_sleep(1);
      }
      __syncthreads();
    }
  }
}

extern "C" void kernel_launch(void* const* d_in, const int* in_sizes, int n_in,
                              void* d_out, int out_size, void* d_ws, size_t ws_size,
                              hipStream_t stream) {
  const float* xin     = (const float*)d_in[0];
  const float* encWih  = (const float*)d_in[1];
  const float* encWhh  = (const float*)d_in[2];
  const float* enc_bih = (const float*)d_in[3];
  const float* enc_bhh = (const float*)d_in[4];
  const float* decWih  = (const float*)d_in[5];
  const float* decWhh  = (const float*)d_in[6];
  const float* dec_bih = (const float*)d_in[7];
  const float* dec_bhh = (const float*)d_in[8];
  const float* linW    = (const float*)d_in[9];
  const float* linb    = (const float*)d_in[10];
  float* out = (float*)d_out;
  char* ws = (char*)d_ws;
  int* cnt = (int*)ws;                          // [0,8192): barrier counters (1KB apart)
  _Float16* hbuf = (_Float16*)(ws + 8192);      // [8192, 8192+1MB): h double buffer

  // zero d_out (pred accumulator) + counters + h buffers, every launch
  init_zero<<<512, 256, 0, stream>>>(out, 1000*512, (float*)ws,
                                     (8192 + 2*512*512*2)/4);

  lstm_main<<<dim3(256), dim3(256), 0, stream>>>(
      xin, encWih, encWhh, enc_bih, enc_bhh,
      decWih, decWhh, dec_bih, dec_bhh,
      linW, linb, out, hbuf, cnt);
}

// Round 5
// 18198.840 us; speedup vs baseline: 2.0768x; 1.6091x over previous
//
#include <hip/hip_runtime.h>

// LSTM seq2seq: 1000 encoder + 1000 decoder steps, B=512, H=512, IN=OUT=1.
// Persistent PLAIN-launch kernel; 256 blocks x 256 threads, 1 block/CU.
// Block (rb,hb): rb=bid>>5 owns batch rows [rb*64,+64); hb=bid&31 owns hidden
// cols [hb*16,+16) -> 64 gate columns. Sync: per-row-group (32 blocks)
// monotonic counter barrier in d_ws.
// ROUND 5: h-exchange granule fix. Round-4 limiter was 4.19M 8B agent-atomic
// loads/step serialized at the LLC atomic pipes (~13.6us/step computed ~= 14.8
// observed). Now each block stages its 64x512 fp16 h tile into LDS ONCE per
// step via global_load_lds aux=sc0|sc1 (16B line-path reads, LLC-coherent
// across XCDs, dedups the 2x wave duplication), then lane-linear conflict-free
// ds_read_b128 fragments. h stores stay 8B agent atomics (65K/step, cheap).
// Numerics: h fp16; W = W_hi(fp16) + W_lo(fp16*2048)/2048 in registers,
// two MFMA passes (f32 accum). Rest fp32.  [absmax 6.1e-5, 4.6x margin]

typedef _Float16 f16x8 __attribute__((ext_vector_type(8)));
typedef _Float16 f16x4 __attribute__((ext_vector_type(4)));
typedef float    f32x4 __attribute__((ext_vector_type(4)));
typedef unsigned long long u64;

// 16B global->LDS async copy, sc0|sc1 (bypass L1+L2 -> read at LLC coherence
// point; correct for cross-XCD producer/consumer regardless of placement).
#define GLOAD_LDS16(gp, lp)                                                    \
  __builtin_amdgcn_global_load_lds(                                            \
      (const __attribute__((address_space(1))) void*)(gp),                     \
      (__attribute__((address_space(3))) void*)(lp), 16, 0, 17)

__device__ __forceinline__ void store_h8_llc(_Float16* p, f16x4 v) {
  __hip_atomic_store((u64*)p, __builtin_bit_cast(u64, v),
                     __ATOMIC_RELAXED, __HIP_MEMORY_SCOPE_AGENT);
}

__global__ void init_zero(float* __restrict__ out, int nout,
                          float* __restrict__ wsf, int nws) {
  int i = blockIdx.x*blockDim.x + threadIdx.x;
  int st = gridDim.x*blockDim.x;
  // agent-scope write-through stores: nothing left dirty in any L2
  for (int j=i; j<nout; j+=st)
    __hip_atomic_store(&out[j], 0.f, __ATOMIC_RELAXED, __HIP_MEMORY_SCOPE_AGENT);
  for (int j=i; j<nws;  j+=st)
    __hip_atomic_store(&wsf[j], 0.f, __ATOMIC_RELAXED, __HIP_MEMORY_SCOPE_AGENT);
}

__global__ __launch_bounds__(256, 1) void lstm_main(
    const float* __restrict__ xin,                              // [1000][512]
    const float* __restrict__ encWih, const float* __restrict__ encWhh,
    const float* __restrict__ enc_bih, const float* __restrict__ enc_bhh,
    const float* __restrict__ decWih, const float* __restrict__ decWhh,
    const float* __restrict__ dec_bih, const float* __restrict__ dec_bhh,
    const float* __restrict__ linW, const float* __restrict__ linb,
    float* __restrict__ out,                                    // [1000][512]
    _Float16* __restrict__ hbuf,                                // [2][512][512]
    int* __restrict__ cnt)                                      // 8 counters, 1KB apart
{
  // h tile in FRAGMENT order: chunk = slice*2048 + (ks*2+half)*64 + lane,
  // where slice=wave-row (32 rows), half=a0/a1 (16-row halves), so MFMA
  // A-fragment reads are lane-linear ds_read_b128 (conflict-free).
  __shared__ f16x8 h_lds[4096];     // 64 KB
  __shared__ float gates[64][68];   // 17408 B; +4 pad kills stride conflicts

  const int bid = blockIdx.x, tid = threadIdx.x;
  const int rb = bid >> 5, hb = bid & 31;
  const int wid = tid >> 6, lane = tid & 63;
  const int wrow = wid >> 1, wcol = wid & 1;         // wave grid 2x2
  const int lcol = lane & 15, lq = lane >> 4, kq = lq*8;

  // cell-update role: thread owns 4 cells (b_local, hidden cols u0..u0+3)
  const int b_local = tid >> 2, u0 = (tid & 3)*4;
  const int bg = rb*64 + b_local;
  const int jh0 = hb*16 + u0;

  float linw[4];
  #pragma unroll
  for (int u=0; u<4; ++u) linw[u] = linW[jh0+u];
  const float linbv = linb[0];

  f16x8 wHi[2][16], wLo[2][16];     // [coltile][kstep], 128 VGPRs
  float biasv[16], wihv[16];        // [gate*4+u]
  float c[4] = {0.f, 0.f, 0.f, 0.f};
  int* mycnt = cnt + rb*256;        // 1KB apart per group

  // staging source offset (halves) for chunk c = i*256+tid, step-invariant
  int goff[16];
  #pragma unroll
  for (int i=0; i<16; ++i) {
    const int cch = i*256 + tid;
    const int pair = (cch >> 6) & 31;          // (c&2047)>>6
    const int ks = pair >> 1, half = pair & 1;
    const int row_local = (cch >> 11)*32 + half*16 + lcol;
    goff[i] = row_local*512 + ks*32 + kq;
  }

  auto loadW = [&](const float* Whh, const float* bih, const float* bhh,
                   const float* Wih) {
    #pragma unroll
    for (int ct=0; ct<2; ++ct) {
      const int g = wcol*2 + ct;                       // gate index 0..3
      const float* wr = Whh + (size_t)(g*512 + hb*16 + lcol)*512;
      #pragma unroll
      for (int ks=0; ks<16; ++ks) {
        f16x8 hi, lo;
        #pragma unroll
        for (int i=0; i<8; ++i) {
          float w = wr[ks*32 + kq + i];
          _Float16 hh = (_Float16)w;
          float hf = (float)hh;
          float rem = (w - hf)*2048.0f;
          if (fabsf(hf) < 6.104e-5f) { hh = (_Float16)0.0f; rem = w*2048.0f; }  // fp16-subnormal guard
          hi[i] = hh; lo[i] = (_Float16)rem;
        }
        wHi[ct][ks] = hi; wLo[ct][ks] = lo;
      }
    }
    #pragma unroll
    for (int g=0; g<4; ++g) {
      #pragma unroll
      for (int u=0; u<4; ++u) {
        int j = g*512 + jh0 + u;
        biasv[g*4+u] = bih[j] + bhh[j];
        wihv[g*4+u]  = Wih[j];          // IN==1: Wih is [2048][1]
      }
    }
  };

  loadW(encWhh, enc_bih, enc_bhh, encWih);

  int epoch = 0;
  for (int s=0; s<2000; ++s) {
    if (s == 1000) {                       // enc -> dec weight switch (post-barrier, safe)
      loadW(decWhh, dec_bih, dec_bhh, decWih);
    }
    const bool dec = (s >= 1000);
    const int td = s - 1000;
    const _Float16* hr = hbuf + (size_t)((s+1)&1)*(512*512);  // reads h_{s-1}
    _Float16*       hw = hbuf + (size_t)( s   &1)*(512*512);  // writes h_s

    // hoist x early: its LLC latency hides under staging + MFMA
    float x;
    if (!dec) x = xin[(size_t)s*512 + bg];
    else      x = (td > 0) ? __hip_atomic_load(&out[(size_t)(td-1)*512 + bg],
                                               __ATOMIC_RELAXED, __HIP_MEMORY_SCOPE_AGENT)
                           : 0.0f;

    // ---- stage this block's 64x512 fp16 h tile into LDS (64 KB, once) ----
    const _Float16* hrb = hr + (size_t)rb*64*512;   // contiguous 64-row tile
    {
      f16x8* ldst = &h_lds[(size_t)wid*64];         // wave-uniform base
      #pragma unroll
      for (int i=0; i<16; ++i)
        GLOAD_LDS16(hrb + goff[i], ldst + i*256);
    }
    __syncthreads();   // drains vmcnt(0) -> staged tile visible to all waves

    // ---- gates = h @ W^T  (2-pass MFMA, wave tile 32 rows x 32 gate cols) ----
    f32x4 accH[2][2], accL[2][2];
    #pragma unroll
    for (int rt=0; rt<2; ++rt)
      #pragma unroll
      for (int ctt=0; ctt<2; ++ctt) {
        accH[rt][ctt] = {0.f,0.f,0.f,0.f};
        accL[rt][ctt] = {0.f,0.f,0.f,0.f};
      }

    const f16x8* Ha = &h_lds[(size_t)wrow*2048];
    #pragma unroll
    for (int ks=0; ks<16; ++ks) {
      const f16x8 a0 = Ha[ks*128 + lane];        // ds_read_b128, lane-linear
      const f16x8 a1 = Ha[ks*128 + 64 + lane];
      accH[0][0] = __builtin_amdgcn_mfma_f32_16x16x32_f16(a0, wHi[0][ks], accH[0][0], 0,0,0);
      accH[1][0] = __builtin_amdgcn_mfma_f32_16x16x32_f16(a1, wHi[0][ks], accH[1][0], 0,0,0);
      accH[0][1] = __builtin_amdgcn_mfma_f32_16x16x32_f16(a0, wHi[1][ks], accH[0][1], 0,0,0);
      accH[1][1] = __builtin_amdgcn_mfma_f32_16x16x32_f16(a1, wHi[1][ks], accH[1][1], 0,0,0);
      accL[0][0] = __builtin_amdgcn_mfma_f32_16x16x32_f16(a0, wLo[0][ks], accL[0][0], 0,0,0);
      accL[1][0] = __builtin_amdgcn_mfma_f32_16x16x32_f16(a1, wLo[0][ks], accL[1][0], 0,0,0);
      accL[0][1] = __builtin_amdgcn_mfma_f32_16x16x32_f16(a0, wLo[1][ks], accL[0][1], 0,0,0);
      accL[1][1] = __builtin_amdgcn_mfma_f32_16x16x32_f16(a1, wLo[1][ks], accL[1][1], 0,0,0);
    }

    // C-layout (m89): col = lane&15, row = (lane>>4)*4 + i
    #pragma unroll
    for (int rt=0; rt<2; ++rt) {
      #pragma unroll
      for (int ctt=0; ctt<2; ++ctt) {
        f32x4 v = accH[rt][ctt] + accL[rt][ctt]*(1.0f/2048.0f);
        const int col  = wcol*32 + ctt*16 + lcol;
        const int row0 = wrow*32 + rt*16 + lq*4;
        #pragma unroll
        for (int i=0; i<4; ++i) gates[row0+i][col] = v[i];
      }
    }
    __syncthreads();

    // ---- pointwise LSTM cell update (fp32) ----
    const f32x4 gi = *reinterpret_cast<const f32x4*>(&gates[b_local][ 0 + u0]);
    const f32x4 gf = *reinterpret_cast<const f32x4*>(&gates[b_local][16 + u0]);
    const f32x4 gg = *reinterpret_cast<const f32x4*>(&gates[b_local][32 + u0]);
    const f32x4 go = *reinterpret_cast<const f32x4*>(&gates[b_local][48 + u0]);

    f16x4 hv4;
    float sp = 0.f;
    #pragma unroll
    for (int u=0; u<4; ++u) {
      float ai = gi[u] + biasv[ 0+u] + x*wihv[ 0+u];
      float af = gf[u] + biasv[ 4+u] + x*wihv[ 4+u];
      float ag = gg[u] + biasv[ 8+u] + x*wihv[ 8+u];
      float ao = go[u] + biasv[12+u] + x*wihv[12+u];
      float iv = 1.0f/(1.0f + expf(-ai));
      float fv = 1.0f/(1.0f + expf(-af));
      float gv = tanhf(ag);
      float ov = 1.0f/(1.0f + expf(-ao));
      float cn = fv*c[u] + iv*gv;
      c[u] = cn;
      float hv = ov*tanhf(cn);
      hv4[u] = (_Float16)hv;
      sp += hv*linw[u];
    }
    store_h8_llc(hw + (size_t)bg*512 + jh0, hv4);   // 8B write-through to LLC

    if (dec) {  // pred partial: reduce 4 lanes sharing b, one atomicAdd into d_out
      sp += __shfl_xor(sp, 1);
      sp += __shfl_xor(sp, 2);
      if ((tid & 3) == 0) {
        float v = sp + (hb == 0 ? linbv : 0.f);
        __hip_atomic_fetch_add(&out[(size_t)td*512 + bg], v,
                               __ATOMIC_RELAXED, __HIP_MEMORY_SCOPE_AGENT);
      }
    }

    // ---- row-group barrier (32 blocks), fence-free monotonic counter ----
    if (s != 1999) {
      asm volatile("s_waitcnt vmcnt(0)" ::: "memory");  // h stores at LLC
      __syncthreads();
      ++epoch;
      if (tid == 0) {
        __hip_atomic_fetch_add(mycnt, 1, __ATOMIC_RELAXED, __HIP_MEMORY_SCOPE_AGENT);
        const int target = 32*epoch;
        while (__hip_atomic_load(mycnt, __ATOMIC_RELAXED, __HIP_MEMORY_SCOPE_AGENT) < target)
          __builtin_amdgcn_s_sleep(1);
      }
      __syncthreads();
    }
  }
}

extern "C" void kernel_launch(void* const* d_in, const int* in_sizes, int n_in,
                              void* d_out, int out_size, void* d_ws, size_t ws_size,
                              hipStream_t stream) {
  const float* xin     = (const float*)d_in[0];
  const float* encWih  = (const float*)d_in[1];
  const float* encWhh  = (const float*)d_in[2];
  const float* enc_bih = (const float*)d_in[3];
  const float* enc_bhh = (const float*)d_in[4];
  const float* decWih  = (const float*)d_in[5];
  const float* decWhh  = (const float*)d_in[6];
  const float* dec_bih = (const float*)d_in[7];
  const float* dec_bhh = (const float*)d_in[8];
  const float* linW    = (const float*)d_in[9];
  const float* linb    = (const float*)d_in[10];
  float* out = (float*)d_out;
  char* ws = (char*)d_ws;
  int* cnt = (int*)ws;                          // [0,8192): barrier counters (1KB apart)
  _Float16* hbuf = (_Float16*)(ws + 8192);      // [8192, 8192+1MB): h double buffer

  // zero d_out (pred accumulator) + counters + h buffers, every launch
  init_zero<<<512, 256, 0, stream>>>(out, 1000*512, (float*)ws,
                                     (8192 + 2*512*512*2)/4);

  lstm_main<<<dim3(256), dim3(256), 0, stream>>>(
      xin, encWih, encWhh, enc_bih, enc_bhh,
      decWih, decWhh, dec_bih, dec_bhh,
      linW, linb, out, hbuf, cnt);
}

// Round 6
// 13733.893 us; speedup vs baseline: 2.7520x; 1.3251x over previous
//
#include <hip/hip_runtime.h>

// LSTM seq2seq: 1000 encoder + 1000 decoder steps, B=512, H=512, IN=OUT=1.
// Persistent PLAIN-launch kernel; 256 blocks x 256 threads, 1 block/CU.
// Block (rb,hb): rb=bid>>5 owns batch rows [rb*64,+64); hb=bid&31 owns hidden
// cols [hb*16,+16) -> 64 gate columns.
// ROUND 6: (a) flag-broadcast barrier - per-producer flag STORES (128B-spaced
// lines, value = step#) + wave0 64-lane parallel poll; kills the round-5
// 32-way same-line atomicAdd convoy (~1-1.5us/step) and s_sleep detect lag.
// (b) hardware transcendentals: sigmoid/tanh via __expf + v_rcp (overflow-
// safe forms), ~3-4x fewer VALU instrs in pointwise.
// h exchange: LDS staging via global_load_lds aux=17 (sc0|sc1, L1+L2 bypass,
// LLC-coherent; proven rounds 4-5). h stores = 8B agent atomics.
// Numerics: h fp16; W = W_hi(fp16) + W_lo(fp16*2048)/2048 in registers,
// two MFMA passes (f32 accum). Rest fp32.  [round-5 absmax 6.1e-5]

typedef _Float16 f16x8 __attribute__((ext_vector_type(8)));
typedef _Float16 f16x4 __attribute__((ext_vector_type(4)));
typedef float    f32x4 __attribute__((ext_vector_type(4)));
typedef unsigned long long u64;

// 16B global->LDS async copy, sc0|sc1 (bypass L1+L2 -> read at LLC coherence
// point; correct for cross-XCD producer/consumer regardless of placement).
#define GLOAD_LDS16(gp, lp)                                                    \
  __builtin_amdgcn_global_load_lds(                                            \
      (const __attribute__((address_space(1))) void*)(gp),                     \
      (__attribute__((address_space(3))) void*)(lp), 16, 0, 17)

__device__ __forceinline__ void store_h8_llc(_Float16* p, f16x4 v) {
  __hip_atomic_store((u64*)p, __builtin_bit_cast(u64, v),
                     __ATOMIC_RELAXED, __HIP_MEMORY_SCOPE_AGENT);
}

// sigmoid(x) = rcp(1 + e^-x); e^-x -> inf for x<<0 gives rcp(inf)=0: safe.
__device__ __forceinline__ float sigm(float x) {
  return __builtin_amdgcn_rcpf(1.0f + __expf(-x));
}
// tanh(x) = sign(x) * (1-r)*rcp(1+r), r = e^(-2|x|) in (0,1]: overflow-free.
__device__ __forceinline__ float tanh_fast(float x) {
  float r = __expf(-2.0f*fabsf(x));
  float t = (1.0f - r)*__builtin_amdgcn_rcpf(1.0f + r);
  return copysignf(t, x);
}

__global__ void init_zero(float* __restrict__ out, int nout,
                          float* __restrict__ wsf, int nws) {
  int i = blockIdx.x*blockDim.x + threadIdx.x;
  int st = gridDim.x*blockDim.x;
  // agent-scope write-through stores: nothing left dirty in any L2
  for (int j=i; j<nout; j+=st)
    __hip_atomic_store(&out[j], 0.f, __ATOMIC_RELAXED, __HIP_MEMORY_SCOPE_AGENT);
  for (int j=i; j<nws;  j+=st)
    __hip_atomic_store(&wsf[j], 0.f, __ATOMIC_RELAXED, __HIP_MEMORY_SCOPE_AGENT);
}

__global__ __launch_bounds__(256, 1) void lstm_main(
    const float* __restrict__ xin,                              // [1000][512]
    const float* __restrict__ encWih, const float* __restrict__ encWhh,
    const float* __restrict__ enc_bih, const float* __restrict__ enc_bhh,
    const float* __restrict__ decWih, const float* __restrict__ decWhh,
    const float* __restrict__ dec_bih, const float* __restrict__ dec_bhh,
    const float* __restrict__ linW, const float* __restrict__ linb,
    float* __restrict__ out,                                    // [1000][512]
    _Float16* __restrict__ hbuf,                                // [2][512][512]
    int* __restrict__ flags)                                    // 256 x 128B-spaced
{
  // h tile in FRAGMENT order: chunk = slice*2048 + (ks*2+half)*64 + lane,
  // so MFMA A-fragment reads are lane-linear ds_read_b128 (conflict-free).
  __shared__ f16x8 h_lds[4096];     // 64 KB
  __shared__ float gates[64][68];   // 17408 B; +4 pad kills stride conflicts

  const int bid = blockIdx.x, tid = threadIdx.x;
  const int rb = bid >> 5, hb = bid & 31;
  const int wid = tid >> 6, lane = tid & 63;
  const int wrow = wid >> 1, wcol = wid & 1;         // wave grid 2x2
  const int lcol = lane & 15, lq = lane >> 4, kq = lq*8;

  // cell-update role: thread owns 4 cells (b_local, hidden cols u0..u0+3)
  const int b_local = tid >> 2, u0 = (tid & 3)*4;
  const int bg = rb*64 + b_local;
  const int jh0 = hb*16 + u0;

  float linw[4];
  #pragma unroll
  for (int u=0; u<4; ++u) linw[u] = linW[jh0+u];
  const float linbv = linb[0];

  f16x8 wHi[2][16], wLo[2][16];     // [coltile][kstep]
  float biasv[16], wihv[16];        // [gate*4+u]
  float c[4] = {0.f, 0.f, 0.f, 0.f};
  int* myflag = flags + (rb*32 + hb)*32;              // own 128B line
  const int* pollp = flags + (rb*32 + (lane & 31))*32; // lane's producer line

  // staging source offset (halves) for chunk c = i*256+tid, step-invariant
  int goff[16];
  #pragma unroll
  for (int i=0; i<16; ++i) {
    const int cch = i*256 + tid;
    const int pair = (cch >> 6) & 31;          // (c&2047)>>6
    const int ks = pair >> 1, half = pair & 1;
    const int row_local = (cch >> 11)*32 + half*16 + lcol;
    goff[i] = row_local*512 + ks*32 + kq;
  }

  auto loadW = [&](const float* Whh, const float* bih, const float* bhh,
                   const float* Wih) {
    #pragma unroll
    for (int ct=0; ct<2; ++ct) {
      const int g = wcol*2 + ct;                       // gate index 0..3
      const float* wr = Whh + (size_t)(g*512 + hb*16 + lcol)*512;
      #pragma unroll
      for (int ks=0; ks<16; ++ks) {
        f16x8 hi, lo;
        #pragma unroll
        for (int i=0; i<8; ++i) {
          float w = wr[ks*32 + kq + i];
          _Float16 hh = (_Float16)w;
          float hf = (float)hh;
          float rem = (w - hf)*2048.0f;
          if (fabsf(hf) < 6.104e-5f) { hh = (_Float16)0.0f; rem = w*2048.0f; }  // fp16-subnormal guard
          hi[i] = hh; lo[i] = (_Float16)rem;
        }
        wHi[ct][ks] = hi; wLo[ct][ks] = lo;
      }
    }
    #pragma unroll
    for (int g=0; g<4; ++g) {
      #pragma unroll
      for (int u=0; u<4; ++u) {
        int j = g*512 + jh0 + u;
        biasv[g*4+u] = bih[j] + bhh[j];
        wihv[g*4+u]  = Wih[j];          // IN==1: Wih is [2048][1]
      }
    }
  };

  loadW(encWhh, enc_bih, enc_bhh, encWih);

  for (int s=0; s<2000; ++s) {
    if (s == 1000) {                       // enc -> dec weight switch (post-barrier, safe)
      loadW(decWhh, dec_bih, dec_bhh, decWih);
    }
    const bool dec = (s >= 1000);
    const int td = s - 1000;
    const _Float16* hr = hbuf + (size_t)((s+1)&1)*(512*512);  // reads h_{s-1}
    _Float16*       hw = hbuf + (size_t)( s   &1)*(512*512);  // writes h_s

    // hoist x early: its LLC latency hides under staging + MFMA
    float x;
    if (!dec) x = xin[(size_t)s*512 + bg];
    else      x = (td > 0) ? __hip_atomic_load(&out[(size_t)(td-1)*512 + bg],
                                               __ATOMIC_RELAXED, __HIP_MEMORY_SCOPE_AGENT)
                           : 0.0f;

    // ---- stage this block's 64x512 fp16 h tile into LDS (64 KB, once) ----
    const _Float16* hrb = hr + (size_t)rb*64*512;   // contiguous 64-row tile
    {
      f16x8* ldst = &h_lds[(size_t)wid*64];         // wave-uniform base
      #pragma unroll
      for (int i=0; i<16; ++i)
        GLOAD_LDS16(hrb + goff[i], ldst + i*256);
    }
    __syncthreads();   // drains vmcnt(0) -> staged tile visible to all waves

    // ---- gates = h @ W^T  (2-pass MFMA, wave tile 32 rows x 32 gate cols) ----
    f32x4 accH[2][2], accL[2][2];
    #pragma unroll
    for (int rt=0; rt<2; ++rt)
      #pragma unroll
      for (int ctt=0; ctt<2; ++ctt) {
        accH[rt][ctt] = {0.f,0.f,0.f,0.f};
        accL[rt][ctt] = {0.f,0.f,0.f,0.f};
      }

    const f16x8* Ha = &h_lds[(size_t)wrow*2048];
    #pragma unroll
    for (int ks=0; ks<16; ++ks) {
      const f16x8 a0 = Ha[ks*128 + lane];        // ds_read_b128, lane-linear
      const f16x8 a1 = Ha[ks*128 + 64 + lane];
      accH[0][0] = __builtin_amdgcn_mfma_f32_16x16x32_f16(a0, wHi[0][ks], accH[0][0], 0,0,0);
      accH[1][0] = __builtin_amdgcn_mfma_f32_16x16x32_f16(a1, wHi[0][ks], accH[1][0], 0,0,0);
      accH[0][1] = __builtin_amdgcn_mfma_f32_16x16x32_f16(a0, wHi[1][ks], accH[0][1], 0,0,0);
      accH[1][1] = __builtin_amdgcn_mfma_f32_16x16x32_f16(a1, wHi[1][ks], accH[1][1], 0,0,0);
      accL[0][0] = __builtin_amdgcn_mfma_f32_16x16x32_f16(a0, wLo[0][ks], accL[0][0], 0,0,0);
      accL[1][0] = __builtin_amdgcn_mfma_f32_16x16x32_f16(a1, wLo[0][ks], accL[1][0], 0,0,0);
      accL[0][1] = __builtin_amdgcn_mfma_f32_16x16x32_f16(a0, wLo[1][ks], accL[0][1], 0,0,0);
      accL[1][1] = __builtin_amdgcn_mfma_f32_16x16x32_f16(a1, wLo[1][ks], accL[1][1], 0,0,0);
    }

    // C-layout (m89): col = lane&15, row = (lane>>4)*4 + i
    #pragma unroll
    for (int rt=0; rt<2; ++rt) {
      #pragma unroll
      for (int ctt=0; ctt<2; ++ctt) {
        f32x4 v = accH[rt][ctt] + accL[rt][ctt]*(1.0f/2048.0f);
        const int col  = wcol*32 + ctt*16 + lcol;
        const int row0 = wrow*32 + rt*16 + lq*4;
        #pragma unroll
        for (int i=0; i<4; ++i) gates[row0+i][col] = v[i];
      }
    }
    __syncthreads();

    // ---- pointwise LSTM cell update (fp32, HW transcendentals) ----
    const f32x4 gi = *reinterpret_cast<const f32x4*>(&gates[b_local][ 0 + u0]);
    const f32x4 gf = *reinterpret_cast<const f32x4*>(&gates[b_local][16 + u0]);
    const f32x4 gg = *reinterpret_cast<const f32x4*>(&gates[b_local][32 + u0]);
    const f32x4 go = *reinterpret_cast<const f32x4*>(&gates[b_local][48 + u0]);

    f16x4 hv4;
    float sp = 0.f;
    #pragma unroll
    for (int u=0; u<4; ++u) {
      float ai = gi[u] + biasv[ 0+u] + x*wihv[ 0+u];
      float af = gf[u] + biasv[ 4+u] + x*wihv[ 4+u];
      float ag = gg[u] + biasv[ 8+u] + x*wihv[ 8+u];
      float ao = go[u] + biasv[12+u] + x*wihv[12+u];
      float iv = sigm(ai);
      float fv = sigm(af);
      float gv = tanh_fast(ag);
      float ov = sigm(ao);
      float cn = fv*c[u] + iv*gv;
      c[u] = cn;
      float hv = ov*tanh_fast(cn);
      hv4[u] = (_Float16)hv;
      sp += hv*linw[u];
    }
    store_h8_llc(hw + (size_t)bg*512 + jh0, hv4);   // 8B write-through to LLC

    if (dec) {  // pred partial: reduce 4 lanes sharing b, one atomicAdd into d_out
      sp += __shfl_xor(sp, 1);
      sp += __shfl_xor(sp, 2);
      if ((tid & 3) == 0) {
        float v = sp + (hb == 0 ? linbv : 0.f);
        __hip_atomic_fetch_add(&out[(size_t)td*512 + bg], v,
                               __ATOMIC_RELAXED, __HIP_MEMORY_SCOPE_AGENT);
      }
    }

    // ---- row-group barrier (32 blocks): flag-broadcast, no RMW convoy ----
    if (s != 1999) {
      asm volatile("s_waitcnt vmcnt(0)" ::: "memory");  // own h stores/atomics acked
      __syncthreads();                                  // whole block drained
      const int target = s + 1;
      if (tid == 0)
        __hip_atomic_store(myflag, target, __ATOMIC_RELAXED, __HIP_MEMORY_SCOPE_AGENT);
      if (wid == 0) {      // 64 lanes poll 32 producer flags (2 lanes/flag)
        while (!__all(__hip_atomic_load(pollp, __ATOMIC_RELAXED,
                                        __HIP_MEMORY_SCOPE_AGENT) >= target)) { }
      }
      __syncthreads();
    }
  }
}

extern "C" void kernel_launch(void* const* d_in, const int* in_sizes, int n_in,
                              void* d_out, int out_size, void* d_ws, size_t ws_size,
                              hipStream_t stream) {
  const float* xin     = (const float*)d_in[0];
  const float* encWih  = (const float*)d_in[1];
  const float* encWhh  = (const float*)d_in[2];
  const float* enc_bih = (const float*)d_in[3];
  const float* enc_bhh = (const float*)d_in[4];
  const float* decWih  = (const float*)d_in[5];
  const float* decWhh  = (const float*)d_in[6];
  const float* dec_bih = (const float*)d_in[7];
  const float* dec_bhh = (const float*)d_in[8];
  const float* linW    = (const float*)d_in[9];
  const float* linb    = (const float*)d_in[10];
  float* out = (float*)d_out;
  char* ws = (char*)d_ws;
  int* flags = (int*)ws;                        // [0, 32KB): 256 x 128B flag lines
  _Float16* hbuf = (_Float16*)(ws + 32768);     // [32KB, 32KB+1MB): h double buffer

  // zero d_out (pred accumulator) + flags + h buffers, every launch
  init_zero<<<512, 256, 0, stream>>>(out, 1000*512, (float*)ws,
                                     (32768 + 2*512*512*2)/4);

  lstm_main<<<dim3(256), dim3(256), 0, stream>>>(
      xin, encWih, encWhh, enc_bih, enc_bhh,
      decWih, decWhh, dec_bih, dec_bhh,
      linW, linb, out, hbuf, flags);
}